// Round 2
// baseline (466.604 us; speedup 1.0000x reference)
//
#include <hip/hip_runtime.h>
#include <hip/hip_bf16.h>

// FactorizedDenseAttention, MI355X/gfx950.  ALL I/O IS FP32 (per reference).
// Identity: S[i,j] = sum_m C[i,m]*B[j,m], C = 32*(a[2m]+a[2m+1]) (rank 32)
//   a = q@Wa^T+ba (64ch), B = q@Wb^T+bb (32ch); P = softmax(S); O = P@v.
// S via hi/lo bf16 Dekker split of fp32 C,B -> 4 MFMAs (16x16x32), abs err
// ~2e-3 (threshold is 2% of max|ref| per output: 0.101 for O, 0.02 for P).
// Stats pass and P pass run bitwise-identical MFMA sequences so exp(S-m)=1
// exactly at the row max.
// d_out = [O: H*L*64 f32][P: H*L*L f32].

#define HN 16
#define LN 2048
#define KR 32   // rank = MAX_SEQ/F = 32

typedef __attribute__((ext_vector_type(8))) short bf16x8;
typedef __attribute__((ext_vector_type(4))) float f32x4;

__device__ __forceinline__ float b2f(unsigned short u) {
    return __uint_as_float(((unsigned int)u) << 16);
}
__device__ __forceinline__ unsigned short f2b(float f) {
    __hip_bfloat16 h = __float2bfloat16(f);   // RNE
    return *reinterpret_cast<unsigned short*>(&h);
}

// ---------------------------------------------------------------------------
// K1a: per row i: a = q@Wa^T+ba, b = q@Wb^T+bb, C = 32*(a[2m]+a[2m+1]);
// store hi/lo bf16 split of C and B. One thread per row, weights in LDS.
// ---------------------------------------------------------------------------
__global__ __launch_bounds__(128) void k_cb(
    const float* __restrict__ q,
    const float* __restrict__ Wa, const float* __restrict__ ba,
    const float* __restrict__ Wb, const float* __restrict__ bb,
    unsigned short* __restrict__ Chi, unsigned short* __restrict__ Clo,
    unsigned short* __restrict__ Bhi, unsigned short* __restrict__ Blo)
{
    __shared__ float sWa[64 * 64];
    __shared__ float sWb[32 * 64];
    __shared__ float sba[64];
    __shared__ float sbb[32];
    const int tid = threadIdx.x;
    for (int i = tid; i < 64 * 64; i += 128) sWa[i] = Wa[i];
    for (int i = tid; i < 32 * 64; i += 128) sWb[i] = Wb[i];
    if (tid < 64) sba[tid] = ba[tid];
    if (tid < 32) sbb[tid] = bb[tid];
    __syncthreads();

    const int row = blockIdx.x * 128 + tid;           // 0..H*L-1
    float qf[64];
    const float4* q4p = reinterpret_cast<const float4*>(q + (size_t)row * 64);
    #pragma unroll
    for (int k4 = 0; k4 < 16; ++k4) {
        float4 u = q4p[k4];
        qf[4*k4+0] = u.x; qf[4*k4+1] = u.y; qf[4*k4+2] = u.z; qf[4*k4+3] = u.w;
    }
    const int ob = row * KR;
    #pragma unroll 1
    for (int m = 0; m < KR; ++m) {
        float a0 = sba[2*m], a1 = sba[2*m+1], bv = sbb[m];
        const float4* wa0 = reinterpret_cast<const float4*>(&sWa[(2*m) * 64]);
        const float4* wa1 = reinterpret_cast<const float4*>(&sWa[(2*m+1) * 64]);
        const float4* wb0 = reinterpret_cast<const float4*>(&sWb[m * 64]);
        #pragma unroll
        for (int k4 = 0; k4 < 16; ++k4) {
            float4 w0 = wa0[k4], w1 = wa1[k4], w2 = wb0[k4];
            float x0 = qf[4*k4], x1 = qf[4*k4+1], x2 = qf[4*k4+2], x3 = qf[4*k4+3];
            a0 = fmaf(x0, w0.x, a0); a0 = fmaf(x1, w0.y, a0);
            a0 = fmaf(x2, w0.z, a0); a0 = fmaf(x3, w0.w, a0);
            a1 = fmaf(x0, w1.x, a1); a1 = fmaf(x1, w1.y, a1);
            a1 = fmaf(x2, w1.z, a1); a1 = fmaf(x3, w1.w, a1);
            bv = fmaf(x0, w2.x, bv); bv = fmaf(x1, w2.y, bv);
            bv = fmaf(x2, w2.z, bv); bv = fmaf(x3, w2.w, bv);
        }
        float c = 32.f * (a0 + a1);                    // fold repeat factor (exact)
        unsigned short ch = f2b(c);
        float cl = c - b2f(ch);                        // exact residual
        Chi[ob + m] = ch; Clo[ob + m] = f2b(cl);
        unsigned short bh = f2b(bv);
        float bl = bv - b2f(bh);
        Bhi[ob + m] = bh; Blo[ob + m] = f2b(bl);
    }
}

// ---------------------------------------------------------------------------
// K1b: Vt[h][d][j] = bf16(v[h][j][d])  (transpose through LDS)
// ---------------------------------------------------------------------------
__global__ __launch_bounds__(256) void k_vt(
    const float* __restrict__ v, unsigned short* __restrict__ Vt)
{
    __shared__ unsigned short sv[64 * 66];   // [j][d], stride 66
    const int tid = threadIdx.x;
    const int h = blockIdx.x >> 5, jt = blockIdx.x & 31;
    const float* src = v + (size_t)(h * LN + jt * 64) * 64;
    for (int i = tid; i < 4096; i += 256)
        sv[(i >> 6) * 66 + (i & 63)] = f2b(src[i]);
    __syncthreads();
    for (int i = tid; i < 4096; i += 256) {
        int d = i >> 6, j = i & 63;
        Vt[(size_t)(h * 64 + d) * LN + jt * 64 + j] = sv[j * 66 + d];
    }
}

// ---------------------------------------------------------------------------
// K2: row stats. Per wave: 16 rows; S tiles via 4 MFMAs (hi/lo), online
// (m,l) per lane, shfl-xor reduce across the 16 lanes of a quad-group.
// ---------------------------------------------------------------------------
__global__ __launch_bounds__(256) void k_stats(
    const unsigned short* __restrict__ Chi, const unsigned short* __restrict__ Clo,
    const unsigned short* __restrict__ Bhi, const unsigned short* __restrict__ Blo,
    float* __restrict__ rowM, float* __restrict__ rowLinv)
{
    const int h = blockIdx.x >> 5, tile = blockIdx.x & 31;
    const int tid = threadIdx.x, w = tid >> 6, lane = tid & 63;
    const int quad = lane >> 4, n16 = lane & 15;
    const int rbase = tile * 64 + w * 16;
    const int hL = h * LN;

    const bf16x8 ahi = *reinterpret_cast<const bf16x8*>(Chi + (size_t)(hL + rbase + n16) * KR + quad * 8);
    const bf16x8 alo = *reinterpret_cast<const bf16x8*>(Clo + (size_t)(hL + rbase + n16) * KR + quad * 8);

    float m0[4] = {-1e30f, -1e30f, -1e30f, -1e30f};
    float l0[4] = {0.f, 0.f, 0.f, 0.f};

    for (int jc = 0; jc < 32; ++jc) {
        const int jb = jc * 64;
        f32x4 s[4];
        #pragma unroll
        for (int ni = 0; ni < 4; ++ni) {
            const size_t bo = (size_t)(hL + jb + ni * 16 + n16) * KR + quad * 8;
            bf16x8 bhi = *reinterpret_cast<const bf16x8*>(Bhi + bo);
            bf16x8 blo = *reinterpret_cast<const bf16x8*>(Blo + bo);
            f32x4 acc = {0.f, 0.f, 0.f, 0.f};
            acc = __builtin_amdgcn_mfma_f32_16x16x32_bf16(ahi, bhi, acc, 0, 0, 0);
            acc = __builtin_amdgcn_mfma_f32_16x16x32_bf16(ahi, blo, acc, 0, 0, 0);
            acc = __builtin_amdgcn_mfma_f32_16x16x32_bf16(alo, bhi, acc, 0, 0, 0);
            acc = __builtin_amdgcn_mfma_f32_16x16x32_bf16(alo, blo, acc, 0, 0, 0);
            s[ni] = acc;
        }
        #pragma unroll
        for (int r = 0; r < 4; ++r) {
            float v0 = s[0][r], v1 = s[1][r], v2 = s[2][r], v3 = s[3][r];
            float mx = fmaxf(fmaxf(v0, v1), fmaxf(v2, v3));
            float mn = fmaxf(m0[r], mx);
            l0[r] = l0[r] * __expf(m0[r] - mn)
                  + __expf(v0 - mn) + __expf(v1 - mn)
                  + __expf(v2 - mn) + __expf(v3 - mn);
            m0[r] = mn;
        }
    }
    #pragma unroll
    for (int off = 1; off <= 8; off <<= 1) {
        #pragma unroll
        for (int r = 0; r < 4; ++r) {
            float m2 = __shfl_xor(m0[r], off, 64);
            float l2 = __shfl_xor(l0[r], off, 64);
            float mn = fmaxf(m0[r], m2);
            l0[r] = l0[r] * __expf(m0[r] - mn) + l2 * __expf(m2 - mn);
            m0[r] = mn;
        }
    }
    if (n16 == 0) {
        #pragma unroll
        for (int r = 0; r < 4; ++r) {
            const int grow = rbase + quad * 4 + r;
            rowM[hL + grow] = m0[r];
            rowLinv[hL + grow] = 1.f / l0[r];
        }
    }
}

// ---------------------------------------------------------------------------
// K3: recompute S (identical MFMA sequence), P = exp(S-m)*linv.
// P stored fp32 directly from accumulators; bf16 copy staged in LDS for the
// PV A-operand (A[m=lane&15][k=quad*8+j]); Vt rows give contiguous-k B-frags.
// ---------------------------------------------------------------------------
__global__ __launch_bounds__(256) void k_pv(
    const unsigned short* __restrict__ Chi, const unsigned short* __restrict__ Clo,
    const unsigned short* __restrict__ Bhi, const unsigned short* __restrict__ Blo,
    const unsigned short* __restrict__ Vt,
    const float* __restrict__ rowM, const float* __restrict__ rowLinv,
    float* __restrict__ outO, float* __restrict__ outP)
{
    __shared__ unsigned short Ps[4][16 * 72];   // per wave, row stride 72
    const int h = blockIdx.x >> 5, tile = blockIdx.x & 31;
    const int tid = threadIdx.x, w = tid >> 6, lane = tid & 63;
    const int quad = lane >> 4, n16 = lane & 15;
    const int rbase = tile * 64 + w * 16;
    const int hL = h * LN;
    unsigned short* ps = &Ps[w][0];

    const bf16x8 ahi = *reinterpret_cast<const bf16x8*>(Chi + (size_t)(hL + rbase + n16) * KR + quad * 8);
    const bf16x8 alo = *reinterpret_cast<const bf16x8*>(Clo + (size_t)(hL + rbase + n16) * KR + quad * 8);

    float mr[4], li[4];
    #pragma unroll
    for (int r = 0; r < 4; ++r) {
        mr[r] = rowM[hL + rbase + quad * 4 + r];
        li[r] = rowLinv[hL + rbase + quad * 4 + r];
    }
    f32x4 zero = {0.f, 0.f, 0.f, 0.f};
    f32x4 o[4];
    #pragma unroll
    for (int di = 0; di < 4; ++di) o[di] = zero;

    for (int jc = 0; jc < 32; ++jc) {
        const int jb = jc * 64;
        #pragma unroll
        for (int ni = 0; ni < 4; ++ni) {
            const size_t bo = (size_t)(hL + jb + ni * 16 + n16) * KR + quad * 8;
            bf16x8 bhi = *reinterpret_cast<const bf16x8*>(Bhi + bo);
            bf16x8 blo = *reinterpret_cast<const bf16x8*>(Blo + bo);
            f32x4 acc = zero;
            acc = __builtin_amdgcn_mfma_f32_16x16x32_bf16(ahi, bhi, acc, 0, 0, 0);
            acc = __builtin_amdgcn_mfma_f32_16x16x32_bf16(ahi, blo, acc, 0, 0, 0);
            acc = __builtin_amdgcn_mfma_f32_16x16x32_bf16(alo, bhi, acc, 0, 0, 0);
            acc = __builtin_amdgcn_mfma_f32_16x16x32_bf16(alo, blo, acc, 0, 0, 0);
            #pragma unroll
            for (int r = 0; r < 4; ++r) {
                float p = __expf(acc[r] - mr[r]) * li[r];
                outP[(size_t)(hL + rbase + quad * 4 + r) * LN + jb + ni * 16 + n16] = p;
                ps[(quad * 4 + r) * 72 + ni * 16 + n16] = f2b(p);
            }
        }
        // in-wave RAW on ps is ordered by compiler-inserted lgkmcnt waits
        // PV: O += P(chunk) @ V(chunk)   (K=64 -> 2 k-steps)
        #pragma unroll
        for (int ks = 0; ks < 2; ++ks) {
            const bf16x8 pa = *reinterpret_cast<const bf16x8*>(ps + n16 * 72 + ks * 32 + quad * 8);
            #pragma unroll
            for (int di = 0; di < 4; ++di) {
                const bf16x8 vb = *reinterpret_cast<const bf16x8*>(
                    Vt + (size_t)(h * 64 + di * 16 + n16) * LN + jb + ks * 32 + quad * 8);
                o[di] = __builtin_amdgcn_mfma_f32_16x16x32_bf16(pa, vb, o[di], 0, 0, 0);
            }
        }
        __syncthreads();   // WAR guard before next chunk overwrites ps
    }
    #pragma unroll
    for (int di = 0; di < 4; ++di) {
        #pragma unroll
        for (int r = 0; r < 4; ++r) {
            const int grow = rbase + quad * 4 + r;
            outO[(size_t)(hL + grow) * 64 + di * 16 + n16] = o[di][r];
        }
    }
}

// ---------------------------------------------------------------------------
extern "C" void kernel_launch(void* const* d_in, const int* in_sizes, int n_in,
                              void* d_out, int out_size, void* d_ws, size_t ws_size,
                              hipStream_t stream)
{
    (void)in_sizes; (void)n_in; (void)out_size; (void)ws_size;
    const float* q  = (const float*)d_in[0];
    const float* v  = (const float*)d_in[1];
    const float* Wa = (const float*)d_in[2];
    const float* ba = (const float*)d_in[3];
    const float* Wb = (const float*)d_in[4];
    const float* bb = (const float*)d_in[5];
    // d_in[6] = len_q (=2048); shapes static.

    float* out = (float*)d_out;
    char* wsb = (char*)d_ws;
    const size_t CBb = (size_t)HN * LN * KR * 2;   // 2MB per bf16 plane
    unsigned short* Chi = (unsigned short*)(wsb + 0 * CBb);
    unsigned short* Clo = (unsigned short*)(wsb + 1 * CBb);
    unsigned short* Bhi = (unsigned short*)(wsb + 2 * CBb);
    unsigned short* Blo = (unsigned short*)(wsb + 3 * CBb);
    unsigned short* Vt  = (unsigned short*)(wsb + 4 * CBb);     // 4MB
    float* rowM    = (float*)(wsb + 6 * CBb);                   // 128KB
    float* rowLinv = (float*)(wsb + 6 * CBb + (size_t)HN * LN * 4);

    float* outO = out;                          // [H*L*64]
    float* outP = out + (size_t)HN * LN * 64;   // [H*L*L]

    hipLaunchKernelGGL(k_cb, dim3(256), dim3(128), 0, stream,
                       q, Wa, ba, Wb, bb, Chi, Clo, Bhi, Blo);
    hipLaunchKernelGGL(k_vt, dim3(512), dim3(256), 0, stream, v, Vt);
    hipLaunchKernelGGL(k_stats, dim3(512), dim3(256), 0, stream,
                       Chi, Clo, Bhi, Blo, rowM, rowLinv);
    hipLaunchKernelGGL(k_pv, dim3(512), dim3(256), 0, stream,
                       Chi, Clo, Bhi, Blo, Vt, rowM, rowLinv, outO, outP);
}

// Round 3
// 443.207 us; speedup vs baseline: 1.0528x; 1.0528x over previous
//
#include <hip/hip_runtime.h>
#include <hip/hip_bf16.h>

// FactorizedDenseAttention, MI355X/gfx950.  ALL I/O FP32.
// S[i,j] = sum_m C[i,m]*B[j,m], C = 32*(a[2m]+a[2m+1]) (rank 32)
//   a = q@Wa^T+ba (64ch), B = q@Wb^T+bb (32ch); P = softmax(S); O = P@v.
// S via hi/lo bf16 Dekker split of C,B -> 4 MFMAs (16x16x32). Stats and P
// passes run bitwise-identical MFMA sequences so exp(S-m)<=1 exactly.
// d_out = [O: H*L*64 f32][P: H*L*L f32].
// R2: k_pv loop barrier REMOVED (LDS tile is wave-private; lgkmcnt orders
// in-wave), LDS stride 72->68 (bank fix), pointer-bump addressing, k_cb 2x
// thread split.

#define HN 16
#define LN 2048
#define KR 32

typedef __attribute__((ext_vector_type(8))) short bf16x8;
typedef __attribute__((ext_vector_type(4))) float f32x4;

__device__ __forceinline__ float b2f(unsigned short u) {
    return __uint_as_float(((unsigned int)u) << 16);
}
__device__ __forceinline__ unsigned short f2b(float f) {
    __hip_bfloat16 h = __float2bfloat16(f);   // RNE
    return *reinterpret_cast<unsigned short*>(&h);
}

// ---------------------------------------------------------------------------
// K1a: thread = (row, mhalf): 16 m's per thread. Weights in LDS.
// ---------------------------------------------------------------------------
__global__ __launch_bounds__(256) void k_cb(
    const float* __restrict__ q,
    const float* __restrict__ Wa, const float* __restrict__ ba,
    const float* __restrict__ Wb, const float* __restrict__ bb,
    unsigned short* __restrict__ Chi, unsigned short* __restrict__ Clo,
    unsigned short* __restrict__ Bhi, unsigned short* __restrict__ Blo)
{
    __shared__ float sWa[64 * 64];
    __shared__ float sWb[32 * 64];
    __shared__ float sba[64];
    __shared__ float sbb[32];
    const int tid = threadIdx.x;
    for (int i = tid; i < 64 * 64; i += 256) sWa[i] = Wa[i];
    for (int i = tid; i < 32 * 64; i += 256) sWb[i] = Wb[i];
    if (tid < 64) sba[tid] = ba[tid];
    if (tid < 32) sbb[tid] = bb[tid];
    __syncthreads();

    const int t = blockIdx.x * 256 + tid;
    const int row = t >> 1, mh = (t & 1) * 16;        // m in [mh, mh+16)
    float qf[64];
    const float4* q4p = reinterpret_cast<const float4*>(q + (size_t)row * 64);
    #pragma unroll
    for (int k4 = 0; k4 < 16; ++k4) {
        float4 u = q4p[k4];
        qf[4*k4+0] = u.x; qf[4*k4+1] = u.y; qf[4*k4+2] = u.z; qf[4*k4+3] = u.w;
    }
    const int ob = row * KR;
    #pragma unroll 1
    for (int mi = 0; mi < 16; ++mi) {
        const int m = mh + mi;
        float a0 = sba[2*m], a1 = sba[2*m+1], bv = sbb[m];
        const float4* wa0 = reinterpret_cast<const float4*>(&sWa[(2*m) * 64]);
        const float4* wa1 = reinterpret_cast<const float4*>(&sWa[(2*m+1) * 64]);
        const float4* wb0 = reinterpret_cast<const float4*>(&sWb[m * 64]);
        #pragma unroll
        for (int k4 = 0; k4 < 16; ++k4) {
            float4 w0 = wa0[k4], w1 = wa1[k4], w2 = wb0[k4];
            float x0 = qf[4*k4], x1 = qf[4*k4+1], x2 = qf[4*k4+2], x3 = qf[4*k4+3];
            a0 = fmaf(x0, w0.x, a0); a0 = fmaf(x1, w0.y, a0);
            a0 = fmaf(x2, w0.z, a0); a0 = fmaf(x3, w0.w, a0);
            a1 = fmaf(x0, w1.x, a1); a1 = fmaf(x1, w1.y, a1);
            a1 = fmaf(x2, w1.z, a1); a1 = fmaf(x3, w1.w, a1);
            bv = fmaf(x0, w2.x, bv); bv = fmaf(x1, w2.y, bv);
            bv = fmaf(x2, w2.z, bv); bv = fmaf(x3, w2.w, bv);
        }
        float c = 32.f * (a0 + a1);                   // fold repeat factor
        unsigned short ch = f2b(c);
        Chi[ob + m] = ch; Clo[ob + m] = f2b(c - b2f(ch));
        unsigned short bh = f2b(bv);
        Bhi[ob + m] = bh; Blo[ob + m] = f2b(bv - b2f(bh));
    }
}

// ---------------------------------------------------------------------------
// K1b: Vt[h][d][j] = bf16(v[h][j][d])
// ---------------------------------------------------------------------------
__global__ __launch_bounds__(256) void k_vt(
    const float* __restrict__ v, unsigned short* __restrict__ Vt)
{
    __shared__ unsigned short sv[64 * 66];
    const int tid = threadIdx.x;
    const int h = blockIdx.x >> 5, jt = blockIdx.x & 31;
    const float* src = v + (size_t)(h * LN + jt * 64) * 64;
    for (int i = tid; i < 4096; i += 256)
        sv[(i >> 6) * 66 + (i & 63)] = f2b(src[i]);
    __syncthreads();
    for (int i = tid; i < 4096; i += 256) {
        int d = i >> 6, j = i & 63;
        Vt[(size_t)(h * 64 + d) * LN + jt * 64 + j] = sv[j * 66 + d];
    }
}

// ---------------------------------------------------------------------------
// K2: row stats (m, 1/l) via online softmax over MFMA S tiles.
// ---------------------------------------------------------------------------
__global__ __launch_bounds__(256) void k_stats(
    const unsigned short* __restrict__ Chi, const unsigned short* __restrict__ Clo,
    const unsigned short* __restrict__ Bhi, const unsigned short* __restrict__ Blo,
    float* __restrict__ rowM, float* __restrict__ rowLinv)
{
    const int h = blockIdx.x >> 5, tile = blockIdx.x & 31;
    const int tid = threadIdx.x, w = tid >> 6, lane = tid & 63;
    const int quad = lane >> 4, n16 = lane & 15;
    const int rbase = tile * 64 + w * 16;
    const int hL = h * LN;

    const bf16x8 ahi = *reinterpret_cast<const bf16x8*>(Chi + (size_t)(hL + rbase + n16) * KR + quad * 8);
    const bf16x8 alo = *reinterpret_cast<const bf16x8*>(Clo + (size_t)(hL + rbase + n16) * KR + quad * 8);

    const unsigned short* bhiP = Bhi + (size_t)(hL + n16) * KR + quad * 8;
    const unsigned short* bloP = Blo + (size_t)(hL + n16) * KR + quad * 8;

    float m0[4] = {-1e30f, -1e30f, -1e30f, -1e30f};
    float l0[4] = {0.f, 0.f, 0.f, 0.f};

    for (int jc = 0; jc < 32; ++jc) {
        const int jb = jc * 64;
        f32x4 s[4];
        #pragma unroll
        for (int ni = 0; ni < 4; ++ni) {
            const int off = (jb + ni * 16) * KR;
            bf16x8 bhi = *reinterpret_cast<const bf16x8*>(bhiP + off);
            bf16x8 blo = *reinterpret_cast<const bf16x8*>(bloP + off);
            f32x4 acc = {0.f, 0.f, 0.f, 0.f};
            acc = __builtin_amdgcn_mfma_f32_16x16x32_bf16(ahi, bhi, acc, 0, 0, 0);
            acc = __builtin_amdgcn_mfma_f32_16x16x32_bf16(ahi, blo, acc, 0, 0, 0);
            acc = __builtin_amdgcn_mfma_f32_16x16x32_bf16(alo, bhi, acc, 0, 0, 0);
            acc = __builtin_amdgcn_mfma_f32_16x16x32_bf16(alo, blo, acc, 0, 0, 0);
            s[ni] = acc;
        }
        #pragma unroll
        for (int r = 0; r < 4; ++r) {
            float v0 = s[0][r], v1 = s[1][r], v2 = s[2][r], v3 = s[3][r];
            float mx = fmaxf(fmaxf(v0, v1), fmaxf(v2, v3));
            float mn = fmaxf(m0[r], mx);
            l0[r] = l0[r] * __expf(m0[r] - mn)
                  + __expf(v0 - mn) + __expf(v1 - mn)
                  + __expf(v2 - mn) + __expf(v3 - mn);
            m0[r] = mn;
        }
    }
    #pragma unroll
    for (int off = 1; off <= 8; off <<= 1) {
        #pragma unroll
        for (int r = 0; r < 4; ++r) {
            float m2 = __shfl_xor(m0[r], off, 64);
            float l2 = __shfl_xor(l0[r], off, 64);
            float mn = fmaxf(m0[r], m2);
            l0[r] = l0[r] * __expf(m0[r] - mn) + l2 * __expf(m2 - mn);
            m0[r] = mn;
        }
    }
    if (n16 == 0) {
        #pragma unroll
        for (int r = 0; r < 4; ++r) {
            const int grow = rbase + quad * 4 + r;
            rowM[hL + grow] = m0[r];
            rowLinv[hL + grow] = 1.f / l0[r];
        }
    }
}

// ---------------------------------------------------------------------------
// K3: recompute S, P = exp(S-m)/l -> fp32 store + bf16 LDS (wave-private,
// NO barrier: in-wave LDS hazards ordered by lgkmcnt), PV MFMA from LDS.
// ---------------------------------------------------------------------------
__global__ __launch_bounds__(256) void k_pv(
    const unsigned short* __restrict__ Chi, const unsigned short* __restrict__ Clo,
    const unsigned short* __restrict__ Bhi, const unsigned short* __restrict__ Blo,
    const unsigned short* __restrict__ Vt,
    const float* __restrict__ rowM, const float* __restrict__ rowLinv,
    float* __restrict__ outO, float* __restrict__ outP)
{
    __shared__ unsigned short Ps[4][16 * 68];   // per wave, row stride 68
    const int h = blockIdx.x >> 5, tile = blockIdx.x & 31;
    const int tid = threadIdx.x, w = tid >> 6, lane = tid & 63;
    const int quad = lane >> 4, n16 = lane & 15;
    const int rbase = tile * 64 + w * 16;
    const int hL = h * LN;
    unsigned short* ps = &Ps[w][0];

    const bf16x8 ahi = *reinterpret_cast<const bf16x8*>(Chi + (size_t)(hL + rbase + n16) * KR + quad * 8);
    const bf16x8 alo = *reinterpret_cast<const bf16x8*>(Clo + (size_t)(hL + rbase + n16) * KR + quad * 8);

    const unsigned short* bhiP = Bhi + (size_t)(hL + n16) * KR + quad * 8;
    const unsigned short* bloP = Blo + (size_t)(hL + n16) * KR + quad * 8;

    const unsigned short* vrow[4];
    #pragma unroll
    for (int di = 0; di < 4; ++di)
        vrow[di] = Vt + (size_t)(h * 64 + di * 16 + n16) * LN + quad * 8;

    float mr[4], li[4];
    float* pP[4];
    #pragma unroll
    for (int r = 0; r < 4; ++r) {
        mr[r] = rowM[hL + rbase + quad * 4 + r];
        li[r] = rowLinv[hL + rbase + quad * 4 + r];
        pP[r] = outP + (size_t)(hL + rbase + quad * 4 + r) * LN + n16;
    }
    f32x4 zero = {0.f, 0.f, 0.f, 0.f};
    f32x4 o[4];
    #pragma unroll
    for (int di = 0; di < 4; ++di) o[di] = zero;

    for (int jc = 0; jc < 32; ++jc) {
        const int jb = jc * 64;
        #pragma unroll
        for (int ni = 0; ni < 4; ++ni) {
            const int off = (jb + ni * 16) * KR;
            bf16x8 bhi = *reinterpret_cast<const bf16x8*>(bhiP + off);
            bf16x8 blo = *reinterpret_cast<const bf16x8*>(bloP + off);
            f32x4 acc = zero;
            acc = __builtin_amdgcn_mfma_f32_16x16x32_bf16(ahi, bhi, acc, 0, 0, 0);
            acc = __builtin_amdgcn_mfma_f32_16x16x32_bf16(ahi, blo, acc, 0, 0, 0);
            acc = __builtin_amdgcn_mfma_f32_16x16x32_bf16(alo, bhi, acc, 0, 0, 0);
            acc = __builtin_amdgcn_mfma_f32_16x16x32_bf16(alo, blo, acc, 0, 0, 0);
            #pragma unroll
            for (int r = 0; r < 4; ++r) {
                float p = __expf(acc[r] - mr[r]) * li[r];
                pP[r][jb + ni * 16] = p;
                ps[(quad * 4 + r) * 68 + ni * 16 + n16] = f2b(p);
            }
        }
        // PV: O += P(chunk) @ V(chunk); in-wave LDS RAW/WAR handled by lgkmcnt
        #pragma unroll
        for (int ks = 0; ks < 2; ++ks) {
            const bf16x8 pa = *reinterpret_cast<const bf16x8*>(ps + n16 * 68 + ks * 32 + quad * 8);
            #pragma unroll
            for (int di = 0; di < 4; ++di) {
                const bf16x8 vb = *reinterpret_cast<const bf16x8*>(vrow[di] + jb + ks * 32);
                o[di] = __builtin_amdgcn_mfma_f32_16x16x32_bf16(pa, vb, o[di], 0, 0, 0);
            }
        }
    }
    #pragma unroll
    for (int di = 0; di < 4; ++di) {
        #pragma unroll
        for (int r = 0; r < 4; ++r) {
            const int grow = rbase + quad * 4 + r;
            outO[(size_t)(hL + grow) * 64 + di * 16 + n16] = o[di][r];
        }
    }
}

// ---------------------------------------------------------------------------
extern "C" void kernel_launch(void* const* d_in, const int* in_sizes, int n_in,
                              void* d_out, int out_size, void* d_ws, size_t ws_size,
                              hipStream_t stream)
{
    (void)in_sizes; (void)n_in; (void)out_size; (void)ws_size;
    const float* q  = (const float*)d_in[0];
    const float* v  = (const float*)d_in[1];
    const float* Wa = (const float*)d_in[2];
    const float* ba = (const float*)d_in[3];
    const float* Wb = (const float*)d_in[4];
    const float* bb = (const float*)d_in[5];

    float* out = (float*)d_out;
    char* wsb = (char*)d_ws;
    const size_t CBb = (size_t)HN * LN * KR * 2;   // 2MB per bf16 plane
    unsigned short* Chi = (unsigned short*)(wsb + 0 * CBb);
    unsigned short* Clo = (unsigned short*)(wsb + 1 * CBb);
    unsigned short* Bhi = (unsigned short*)(wsb + 2 * CBb);
    unsigned short* Blo = (unsigned short*)(wsb + 3 * CBb);
    unsigned short* Vt  = (unsigned short*)(wsb + 4 * CBb);     // 4MB
    float* rowM    = (float*)(wsb + 6 * CBb);
    float* rowLinv = (float*)(wsb + 6 * CBb + (size_t)HN * LN * 4);

    float* outO = out;                          // [H*L*64]
    float* outP = out + (size_t)HN * LN * 64;   // [H*L*L]

    hipLaunchKernelGGL(k_cb, dim3(256), dim3(256), 0, stream,
                       q, Wa, ba, Wb, bb, Chi, Clo, Bhi, Blo);
    hipLaunchKernelGGL(k_vt, dim3(512), dim3(256), 0, stream, v, Vt);
    hipLaunchKernelGGL(k_stats, dim3(512), dim3(256), 0, stream,
                       Chi, Clo, Bhi, Blo, rowM, rowLinv);
    hipLaunchKernelGGL(k_pv, dim3(512), dim3(256), 0, stream,
                       Chi, Clo, Bhi, Blo, Vt, rowM, rowLinv, outO, outP);
}

// Round 4
// 400.628 us; speedup vs baseline: 1.1647x; 1.1063x over previous
//
#include <hip/hip_runtime.h>
#include <hip/hip_bf16.h>

// FactorizedDenseAttention, MI355X/gfx950.  ALL I/O FP32.
// S[i,j] = sum_m C[i,m]*B[j,m], C = 32*(a[2m]+a[2m+1]) (rank 32)
//   a = q@Wa^T+ba (64ch), B = q@Wb^T+bb (32ch); P = softmax(S); O = P@v.
// S via hi/lo bf16 Dekker split -> 4 MFMAs (16x16x32). Stats and P passes
// run bitwise-identical MFMA sequences so exp(S-m)<=1 with equality at max.
// d_out = [O: H*L*64 f32][P: H*L*L f32].
// R4: (1) nontemporal stores for P/O (don't evict B/Vt from L2),
//     (2) k_stats j-split into 2 halves (2x waves), k_pv merges (m,l) pairs.

#define HN 16
#define LN 2048
#define KR 32

typedef __attribute__((ext_vector_type(8))) short bf16x8;
typedef __attribute__((ext_vector_type(4))) float f32x4;

__device__ __forceinline__ float b2f(unsigned short u) {
    return __uint_as_float(((unsigned int)u) << 16);
}
__device__ __forceinline__ unsigned short f2b(float f) {
    __hip_bfloat16 h = __float2bfloat16(f);   // RNE
    return *reinterpret_cast<unsigned short*>(&h);
}

// ---------------------------------------------------------------------------
// K1a: thread = (row, mhalf): 16 m's per thread. Weights in LDS.
// ---------------------------------------------------------------------------
__global__ __launch_bounds__(256) void k_cb(
    const float* __restrict__ q,
    const float* __restrict__ Wa, const float* __restrict__ ba,
    const float* __restrict__ Wb, const float* __restrict__ bb,
    unsigned short* __restrict__ Chi, unsigned short* __restrict__ Clo,
    unsigned short* __restrict__ Bhi, unsigned short* __restrict__ Blo)
{
    __shared__ float sWa[64 * 64];
    __shared__ float sWb[32 * 64];
    __shared__ float sba[64];
    __shared__ float sbb[32];
    const int tid = threadIdx.x;
    for (int i = tid; i < 64 * 64; i += 256) sWa[i] = Wa[i];
    for (int i = tid; i < 32 * 64; i += 256) sWb[i] = Wb[i];
    if (tid < 64) sba[tid] = ba[tid];
    if (tid < 32) sbb[tid] = bb[tid];
    __syncthreads();

    const int t = blockIdx.x * 256 + tid;
    const int row = t >> 1, mh = (t & 1) * 16;        // m in [mh, mh+16)
    float qf[64];
    const float4* q4p = reinterpret_cast<const float4*>(q + (size_t)row * 64);
    #pragma unroll
    for (int k4 = 0; k4 < 16; ++k4) {
        float4 u = q4p[k4];
        qf[4*k4+0] = u.x; qf[4*k4+1] = u.y; qf[4*k4+2] = u.z; qf[4*k4+3] = u.w;
    }
    const int ob = row * KR;
    #pragma unroll 1
    for (int mi = 0; mi < 16; ++mi) {
        const int m = mh + mi;
        float a0 = sba[2*m], a1 = sba[2*m+1], bv = sbb[m];
        const float4* wa0 = reinterpret_cast<const float4*>(&sWa[(2*m) * 64]);
        const float4* wa1 = reinterpret_cast<const float4*>(&sWa[(2*m+1) * 64]);
        const float4* wb0 = reinterpret_cast<const float4*>(&sWb[m * 64]);
        #pragma unroll
        for (int k4 = 0; k4 < 16; ++k4) {
            float4 w0 = wa0[k4], w1 = wa1[k4], w2 = wb0[k4];
            float x0 = qf[4*k4], x1 = qf[4*k4+1], x2 = qf[4*k4+2], x3 = qf[4*k4+3];
            a0 = fmaf(x0, w0.x, a0); a0 = fmaf(x1, w0.y, a0);
            a0 = fmaf(x2, w0.z, a0); a0 = fmaf(x3, w0.w, a0);
            a1 = fmaf(x0, w1.x, a1); a1 = fmaf(x1, w1.y, a1);
            a1 = fmaf(x2, w1.z, a1); a1 = fmaf(x3, w1.w, a1);
            bv = fmaf(x0, w2.x, bv); bv = fmaf(x1, w2.y, bv);
            bv = fmaf(x2, w2.z, bv); bv = fmaf(x3, w2.w, bv);
        }
        float c = 32.f * (a0 + a1);                   // fold repeat factor
        unsigned short ch = f2b(c);
        Chi[ob + m] = ch; Clo[ob + m] = f2b(c - b2f(ch));
        unsigned short bh = f2b(bv);
        Bhi[ob + m] = bh; Blo[ob + m] = f2b(bv - b2f(bh));
    }
}

// ---------------------------------------------------------------------------
// K1b: Vt[h][d][j] = bf16(v[h][j][d])
// ---------------------------------------------------------------------------
__global__ __launch_bounds__(256) void k_vt(
    const float* __restrict__ v, unsigned short* __restrict__ Vt)
{
    __shared__ unsigned short sv[64 * 66];
    const int tid = threadIdx.x;
    const int h = blockIdx.x >> 5, jt = blockIdx.x & 31;
    const float* src = v + (size_t)(h * LN + jt * 64) * 64;
    for (int i = tid; i < 4096; i += 256)
        sv[(i >> 6) * 66 + (i & 63)] = f2b(src[i]);
    __syncthreads();
    for (int i = tid; i < 4096; i += 256) {
        int d = i >> 6, j = i & 63;
        Vt[(size_t)(h * 64 + d) * LN + jt * 64 + j] = sv[j * 66 + d];
    }
}

// ---------------------------------------------------------------------------
// K2: partial row stats over one j-half (16 chunks). Writes (m, l) per
// (row, jhalf); k_pv merges. 1024 blocks -> 4096 waves (4/SIMD).
// ---------------------------------------------------------------------------
__global__ __launch_bounds__(256) void k_stats(
    const unsigned short* __restrict__ Chi, const unsigned short* __restrict__ Clo,
    const unsigned short* __restrict__ Bhi, const unsigned short* __restrict__ Blo,
    float* __restrict__ rowM2, float* __restrict__ rowL2)
{
    const int bx = blockIdx.x;
    const int jh = bx & 1;                   // j-half
    const int tile = (bx >> 1) & 31;
    const int h = bx >> 6;
    const int tid = threadIdx.x, w = tid >> 6, lane = tid & 63;
    const int quad = lane >> 4, n16 = lane & 15;
    const int rbase = tile * 64 + w * 16;
    const int hL = h * LN;

    const bf16x8 ahi = *reinterpret_cast<const bf16x8*>(Chi + (size_t)(hL + rbase + n16) * KR + quad * 8);
    const bf16x8 alo = *reinterpret_cast<const bf16x8*>(Clo + (size_t)(hL + rbase + n16) * KR + quad * 8);

    const unsigned short* bhiP = Bhi + (size_t)(hL + n16) * KR + quad * 8;
    const unsigned short* bloP = Blo + (size_t)(hL + n16) * KR + quad * 8;

    float m0[4] = {-1e30f, -1e30f, -1e30f, -1e30f};
    float l0[4] = {0.f, 0.f, 0.f, 0.f};

    for (int jc = jh * 16; jc < jh * 16 + 16; ++jc) {
        const int jb = jc * 64;
        f32x4 s[4];
        #pragma unroll
        for (int ni = 0; ni < 4; ++ni) {
            const int off = (jb + ni * 16) * KR;
            bf16x8 bhi = *reinterpret_cast<const bf16x8*>(bhiP + off);
            bf16x8 blo = *reinterpret_cast<const bf16x8*>(bloP + off);
            f32x4 acc = {0.f, 0.f, 0.f, 0.f};
            acc = __builtin_amdgcn_mfma_f32_16x16x32_bf16(ahi, bhi, acc, 0, 0, 0);
            acc = __builtin_amdgcn_mfma_f32_16x16x32_bf16(ahi, blo, acc, 0, 0, 0);
            acc = __builtin_amdgcn_mfma_f32_16x16x32_bf16(alo, bhi, acc, 0, 0, 0);
            acc = __builtin_amdgcn_mfma_f32_16x16x32_bf16(alo, blo, acc, 0, 0, 0);
            s[ni] = acc;
        }
        #pragma unroll
        for (int r = 0; r < 4; ++r) {
            float v0 = s[0][r], v1 = s[1][r], v2 = s[2][r], v3 = s[3][r];
            float mx = fmaxf(fmaxf(v0, v1), fmaxf(v2, v3));
            float mn = fmaxf(m0[r], mx);
            l0[r] = l0[r] * __expf(m0[r] - mn)
                  + __expf(v0 - mn) + __expf(v1 - mn)
                  + __expf(v2 - mn) + __expf(v3 - mn);
            m0[r] = mn;
        }
    }
    #pragma unroll
    for (int off = 1; off <= 8; off <<= 1) {
        #pragma unroll
        for (int r = 0; r < 4; ++r) {
            float m2 = __shfl_xor(m0[r], off, 64);
            float l2 = __shfl_xor(l0[r], off, 64);
            float mn = fmaxf(m0[r], m2);
            l0[r] = l0[r] * __expf(m0[r] - mn) + l2 * __expf(m2 - mn);
            m0[r] = mn;
        }
    }
    if (n16 == 0) {
        #pragma unroll
        for (int r = 0; r < 4; ++r) {
            const int grow = rbase + quad * 4 + r;
            rowM2[(size_t)(hL + grow) * 2 + jh] = m0[r];
            rowL2[(size_t)(hL + grow) * 2 + jh] = l0[r];
        }
    }
}

// ---------------------------------------------------------------------------
// K3: merge (m,l) halves, recompute S, P = exp(S-m)/l.
// P/O stored NONTEMPORAL (write-once, keep B/Vt resident in L2).
// bf16 P staged in wave-private LDS for the PV A-operand.
// ---------------------------------------------------------------------------
__global__ __launch_bounds__(256) void k_pv(
    const unsigned short* __restrict__ Chi, const unsigned short* __restrict__ Clo,
    const unsigned short* __restrict__ Bhi, const unsigned short* __restrict__ Blo,
    const unsigned short* __restrict__ Vt,
    const float* __restrict__ rowM2, const float* __restrict__ rowL2,
    float* __restrict__ outO, float* __restrict__ outP)
{
    __shared__ unsigned short Ps[4][16 * 68];   // per wave, row stride 68
    const int h = blockIdx.x >> 5, tile = blockIdx.x & 31;
    const int tid = threadIdx.x, w = tid >> 6, lane = tid & 63;
    const int quad = lane >> 4, n16 = lane & 15;
    const int rbase = tile * 64 + w * 16;
    const int hL = h * LN;
    unsigned short* ps = &Ps[w][0];

    const bf16x8 ahi = *reinterpret_cast<const bf16x8*>(Chi + (size_t)(hL + rbase + n16) * KR + quad * 8);
    const bf16x8 alo = *reinterpret_cast<const bf16x8*>(Clo + (size_t)(hL + rbase + n16) * KR + quad * 8);

    const unsigned short* bhiP = Bhi + (size_t)(hL + n16) * KR + quad * 8;
    const unsigned short* bloP = Blo + (size_t)(hL + n16) * KR + quad * 8;

    const unsigned short* vrow[4];
    #pragma unroll
    for (int di = 0; di < 4; ++di)
        vrow[di] = Vt + (size_t)(h * 64 + di * 16 + n16) * LN + quad * 8;

    float mr[4], li[4];
    float* pP[4];
    #pragma unroll
    for (int r = 0; r < 4; ++r) {
        const size_t idx = (size_t)(hL + rbase + quad * 4 + r);
        float mA = rowM2[idx * 2 + 0], mB = rowM2[idx * 2 + 1];
        float lA = rowL2[idx * 2 + 0], lB = rowL2[idx * 2 + 1];
        float m = fmaxf(mA, mB);
        float l = lA * __expf(mA - m) + lB * __expf(mB - m);
        mr[r] = m;
        li[r] = 1.f / l;
        pP[r] = outP + idx * LN + n16;
    }
    f32x4 zero = {0.f, 0.f, 0.f, 0.f};
    f32x4 o[4];
    #pragma unroll
    for (int di = 0; di < 4; ++di) o[di] = zero;

    for (int jc = 0; jc < 32; ++jc) {
        const int jb = jc * 64;
        #pragma unroll
        for (int ni = 0; ni < 4; ++ni) {
            const int off = (jb + ni * 16) * KR;
            bf16x8 bhi = *reinterpret_cast<const bf16x8*>(bhiP + off);
            bf16x8 blo = *reinterpret_cast<const bf16x8*>(bloP + off);
            f32x4 acc = zero;
            acc = __builtin_amdgcn_mfma_f32_16x16x32_bf16(ahi, bhi, acc, 0, 0, 0);
            acc = __builtin_amdgcn_mfma_f32_16x16x32_bf16(ahi, blo, acc, 0, 0, 0);
            acc = __builtin_amdgcn_mfma_f32_16x16x32_bf16(alo, bhi, acc, 0, 0, 0);
            acc = __builtin_amdgcn_mfma_f32_16x16x32_bf16(alo, blo, acc, 0, 0, 0);
            #pragma unroll
            for (int r = 0; r < 4; ++r) {
                float p = __expf(acc[r] - mr[r]) * li[r];
                __builtin_nontemporal_store(p, &pP[r][jb + ni * 16]);
                ps[(quad * 4 + r) * 68 + ni * 16 + n16] = f2b(p);
            }
        }
        // PV: O += P(chunk) @ V(chunk); in-wave LDS RAW/WAR handled by lgkmcnt
        #pragma unroll
        for (int ks = 0; ks < 2; ++ks) {
            const bf16x8 pa = *reinterpret_cast<const bf16x8*>(ps + n16 * 68 + ks * 32 + quad * 8);
            #pragma unroll
            for (int di = 0; di < 4; ++di) {
                const bf16x8 vb = *reinterpret_cast<const bf16x8*>(vrow[di] + jb + ks * 32);
                o[di] = __builtin_amdgcn_mfma_f32_16x16x32_bf16(pa, vb, o[di], 0, 0, 0);
            }
        }
    }
    #pragma unroll
    for (int di = 0; di < 4; ++di) {
        #pragma unroll
        for (int r = 0; r < 4; ++r) {
            const int grow = rbase + quad * 4 + r;
            __builtin_nontemporal_store(o[di][r],
                &outO[(size_t)(hL + grow) * 64 + di * 16 + n16]);
        }
    }
}

// ---------------------------------------------------------------------------
extern "C" void kernel_launch(void* const* d_in, const int* in_sizes, int n_in,
                              void* d_out, int out_size, void* d_ws, size_t ws_size,
                              hipStream_t stream)
{
    (void)in_sizes; (void)n_in; (void)out_size; (void)ws_size;
    const float* q  = (const float*)d_in[0];
    const float* v  = (const float*)d_in[1];
    const float* Wa = (const float*)d_in[2];
    const float* ba = (const float*)d_in[3];
    const float* Wb = (const float*)d_in[4];
    const float* bb = (const float*)d_in[5];

    float* out = (float*)d_out;
    char* wsb = (char*)d_ws;
    const size_t CBb = (size_t)HN * LN * KR * 2;   // 2MB per bf16 plane
    unsigned short* Chi = (unsigned short*)(wsb + 0 * CBb);
    unsigned short* Clo = (unsigned short*)(wsb + 1 * CBb);
    unsigned short* Bhi = (unsigned short*)(wsb + 2 * CBb);
    unsigned short* Blo = (unsigned short*)(wsb + 3 * CBb);
    unsigned short* Vt  = (unsigned short*)(wsb + 4 * CBb);     // 4MB
    float* rowM2 = (float*)(wsb + 6 * CBb);                     // 2*HN*LN f32
    float* rowL2 = (float*)(wsb + 6 * CBb + (size_t)2 * HN * LN * 4);

    float* outO = out;                          // [H*L*64]
    float* outP = out + (size_t)HN * LN * 64;   // [H*L*L]

    hipLaunchKernelGGL(k_cb, dim3(256), dim3(256), 0, stream,
                       q, Wa, ba, Wb, bb, Chi, Clo, Bhi, Blo);
    hipLaunchKernelGGL(k_vt, dim3(512), dim3(256), 0, stream, v, Vt);
    hipLaunchKernelGGL(k_stats, dim3(1024), dim3(256), 0, stream,
                       Chi, Clo, Bhi, Blo, rowM2, rowL2);
    hipLaunchKernelGGL(k_pv, dim3(512), dim3(256), 0, stream,
                       Chi, Clo, Bhi, Blo, Vt, rowM2, rowL2, outO, outP);
}